// Round 1
// baseline (141.312 us; speedup 1.0000x reference)
//
#include <hip/hip_runtime.h>

// Scalar RNN scan: h_t = b3 + sum_j W3[j]*tanh(W1[j]*x_t + b1[j] + b2[j] + W2[j]*h_{t-1})
// TS=2048 steps, BS=16384 independent sequences, FT=1, HID=3.
// One thread per sequence; 256 blocks x 64 threads = 1 wave/CU.
// Memory-bound target: 256 MiB @ ~6.3 TB/s ~= 42 us.

#define TS_ 2048
#define BS_ 16384

constexpr int U  = 32;       // prefetch block depth (steps)
constexpr int NB = TS_ / U;  // 64 blocks

__global__ __launch_bounds__(64)
void rnn_scan_kernel(const float* __restrict__ x,
                     const float* __restrict__ W1, const float* __restrict__ b1,
                     const float* __restrict__ W2, const float* __restrict__ b2,
                     const float* __restrict__ W3, const float* __restrict__ b3,
                     float* __restrict__ out)
{
    const int b = blockIdx.x * blockDim.x + threadIdx.x;

    // Fold 2*log2(e) into the pre-tanh affine so the chain is:
    //   fma -> v_exp_f32 -> add -> v_rcp_f32 -> fma tree
    const float K = 2.885390081777927f; // 2*log2(e)

    const float kw1_0 = K * W1[0], kw1_1 = K * W1[1], kw1_2 = K * W1[2];
    const float kw2_0 = K * W2[0], kw2_1 = K * W2[1], kw2_2 = K * W2[2];
    const float kb_0 = K * (b1[0] + b2[0]);
    const float kb_1 = K * (b1[1] + b2[1]);
    const float kb_2 = K * (b1[2] + b2[2]);
    const float w3_0 = W3[0], w3_1 = W3[1], w3_2 = W3[2];
    // tanh(z) = 1 - 2*r, r = 1/(e+1)  =>  h = (b3 + sum w3) + sum (-2*w3_j)*r_j
    const float Bc  = b3[0] + w3_0 + w3_1 + w3_2;
    const float u_0 = -2.0f * w3_0, u_1 = -2.0f * w3_1, u_2 = -2.0f * w3_2;

    const float* xp = x + b;
    float*       op = out + b;

    // Two 32-deep register prefetch buffers: 32-64 dword loads in flight per
    // wave to cover ~900cy HBM latency at 1 wave/CU.
    float bufA[U], bufB[U];
#pragma unroll
    for (int u = 0; u < U; ++u) bufA[u] = xp[(size_t)u * BS_];
#pragma unroll
    for (int u = 0; u < U; ++u) bufB[u] = xp[(size_t)(U + u) * BS_];

    float h = 0.0f;

#define RNN_STEP(XV, T) do {                                              \
        float xv_ = (XV);                                                 \
        /* off-chain: depends only on x */                                \
        float a0_ = fmaf(kw1_0, xv_, kb_0);                               \
        float a1_ = fmaf(kw1_1, xv_, kb_1);                               \
        float a2_ = fmaf(kw1_2, xv_, kb_2);                               \
        /* critical chain starts here */                                  \
        float z0_ = fmaf(kw2_0, h, a0_);                                  \
        float z1_ = fmaf(kw2_1, h, a1_);                                  \
        float z2_ = fmaf(kw2_2, h, a2_);                                  \
        float r0_ = __builtin_amdgcn_rcpf(__builtin_amdgcn_exp2f(z0_) + 1.0f); \
        float r1_ = __builtin_amdgcn_rcpf(__builtin_amdgcn_exp2f(z1_) + 1.0f); \
        float r2_ = __builtin_amdgcn_rcpf(__builtin_amdgcn_exp2f(z2_) + 1.0f); \
        float t0_ = fmaf(u_0, r0_, Bc);                                   \
        float t1_ = fmaf(u_1, r1_, u_2 * r2_);                            \
        h = t0_ + t1_;                                                    \
        op[(size_t)(T) * BS_] = h;                                        \
    } while (0)

    for (int n = 0; n < NB; n += 2) {
        // compute block n (bufA)
#pragma unroll
        for (int u = 0; u < U; ++u) RNN_STEP(bufA[u], n * U + u);
        // prefetch block n+2 into bufA (hidden under block n+1 compute)
        if (n + 2 < NB) {
#pragma unroll
            for (int u = 0; u < U; ++u) bufA[u] = xp[(size_t)((n + 2) * U + u) * BS_];
        }
        // compute block n+1 (bufB)
#pragma unroll
        for (int u = 0; u < U; ++u) RNN_STEP(bufB[u], (n + 1) * U + u);
        // prefetch block n+3 into bufB
        if (n + 3 < NB) {
#pragma unroll
            for (int u = 0; u < U; ++u) bufB[u] = xp[(size_t)((n + 3) * U + u) * BS_];
        }
    }
#undef RNN_STEP
}

extern "C" void kernel_launch(void* const* d_in, const int* in_sizes, int n_in,
                              void* d_out, int out_size, void* d_ws, size_t ws_size,
                              hipStream_t stream) {
    const float* x  = (const float*)d_in[0];
    const float* W1 = (const float*)d_in[1];
    const float* b1 = (const float*)d_in[2];
    const float* W2 = (const float*)d_in[3];
    const float* b2 = (const float*)d_in[4];
    const float* W3 = (const float*)d_in[5];
    const float* b3 = (const float*)d_in[6];
    float* out = (float*)d_out;

    dim3 block(64);
    dim3 grid(BS_ / 64);  // 256 blocks -> ~1 wave per CU
    rnn_scan_kernel<<<grid, block, 0, stream>>>(x, W1, b1, W2, b2, W3, b3, out);
}